// Round 10
// baseline (231.636 us; speedup 1.0000x reference)
//
#include <hip/hip_runtime.h>

// Problem constants
#define BB 4
#define TT 2048
#define CC 1024
#define C3 3072
#define HH 16
#define HD 64
#define BT 8192   // BB*TT

#define TS 32
#define TSZ (64 * TS)   // u16 elements per 64-row sub-tile (4 KB)

typedef __bf16 bf16x8 __attribute__((ext_vector_type(8)));
typedef float floatx4 __attribute__((ext_vector_type(4)));
typedef unsigned uintx2 __attribute__((ext_vector_type(2)));
typedef unsigned short u16;

__device__ __forceinline__ u16 f2bf(float f) {
  union { float f; unsigned u; } a; a.f = f;
  return (u16)((a.u + 0x7fffu + ((a.u >> 16) & 1u)) >> 16);  // RNE
}
__device__ __forceinline__ bf16x8 ld8(const u16* p) { return *(const bf16x8*)p; }
__device__ __forceinline__ floatx4 mfma16(bf16x8 a, bf16x8 b, floatx4 c) {
  return __builtin_amdgcn_mfma_f32_16x16x32_bf16(a, b, c, 0, 0, 0);
}

// Async global->LDS, 16B/lane. LDS dest = wave-uniform base + lane*16 (m104).
__device__ __forceinline__ void gload16(const u16* g, u16* l) {
  __builtin_amdgcn_global_load_lds(
      (const __attribute__((address_space(1))) void*)g,
      (__attribute__((address_space(3))) void*)l, 16, 0, 0);
}

// qd-group redistribution via permlane32/16_swap (verified R3):
//   r0 = [a@0, a@2, b@0, b@2], r1 = [a@1, a@3, b@1, b@3]  (by qd group)
__device__ __forceinline__ void qd_xchg(unsigned a, unsigned b,
                                        unsigned& r0, unsigned& r1) {
  uintx2 t = __builtin_amdgcn_permlane32_swap(a, b, false, false);
  uintx2 r = __builtin_amdgcn_permlane16_swap(t[0], t[1], false, false);
  r0 = r[0]; r1 = r[1];
}

// compiler-fence + hw barrier (no vmcnt drain, unlike __syncthreads)
#define BARR do { asm volatile("" ::: "memory"); \
                  __builtin_amdgcn_s_barrier(); \
                  asm volatile("" ::: "memory"); } while (0)
#define VMW4  asm volatile("s_waitcnt vmcnt(4)" ::: "memory")
#define VMW0  asm volatile("s_waitcnt vmcnt(0)" ::: "memory")
#define VMNOP do {} while (0)
#define LGKM0 asm volatile("s_waitcnt lgkmcnt(0)" ::: "memory")

// ---------------------------------------------------------------------------
// Fused prep kernel (R8, verified):
//   blocks [0, 8192)    : fp32 -> bf16 for x
//   blocks [8192, 8960) : w_attn -> waT transpose
//   blocks [8960, 9216) : w_proj -> wpT transpose
// ---------------------------------------------------------------------------
__global__ __launch_bounds__(256) void prep_kernel(
    const float4* __restrict__ x4, ushort4* __restrict__ xb4,
    const float* __restrict__ w_attn, u16* __restrict__ waT,
    const float* __restrict__ w_proj, u16* __restrict__ wpT) {
  __shared__ float s[64][65];
  const int t = threadIdx.x;
  const int bid = blockIdx.x;

  if (bid < 8192) {                 // --- tobf16 ---
    const int i = bid * 256 + t;
    float4 v = x4[i];
    ushort4 o; o.x = f2bf(v.x); o.y = f2bf(v.y); o.z = f2bf(v.z); o.w = f2bf(v.w);
    xb4[i] = o;
    return;
  }

  const float* src; u16* dst; int N, bx, by;
  if (bid < 8960) { const int b2 = bid - 8192; src = w_attn; dst = waT; N = C3;
                    bx = b2 % 48; by = b2 / 48; }
  else            { const int b2 = bid - 8960; src = w_proj; dst = wpT; N = CC;
                    bx = b2 % 16; by = b2 / 16; }
  const int K = CC;
  const int r = t >> 4;
  const int c = (t & 15) * 4;
  const int k0 = by * 64, n0 = bx * 64;
#pragma unroll
  for (int i = 0; i < 4; ++i) {
    float4 v = *(const float4*)&src[(size_t)(k0 + r + i * 16) * N + n0 + c];
    s[r + i * 16][c + 0] = v.x; s[r + i * 16][c + 1] = v.y;
    s[r + i * 16][c + 2] = v.z; s[r + i * 16][c + 3] = v.w;
  }
  __syncthreads();
#pragma unroll
  for (int i = 0; i < 4; ++i) {
    const int nn = r + i * 16;
    ushort4 o;
    o.x = f2bf(s[c + 0][nn]); o.y = f2bf(s[c + 1][nn]);
    o.z = f2bf(s[c + 2][nn]); o.w = f2bf(s[c + 3][nn]);
    *(ushort4*)&dst[(size_t)(n0 + nn) * K + k0 + c] = o;
  }
}

// ---------------------------------------------------------------------------
// R10 = R9 qkv GEMM with the DMA-visibility race FIXED.
// m201 geometry: 256x256 block, 512 thr = 8 waves (2M x 4N), per-wave output
// 128x64, BK=64.  LDS 128 KiB = [parity][A0,A1,B0,B1][128x64 u16].
// 16B-granular XOR swizzle: LDS[row][c] = G[row][c ^ ((row&7)*8)].
// Per K-tile: 4 quadrant phases, 16 MFMA each; 24 ds_read_b128 / 64 MFMA.
// Stages: P1: A0(T+1)  P2: A1(T+1)  P3: B0(T+2)  P4: B1(T+2)  (slot-ring;
// each stage targets a slot whose readers drained at a previous barrier).
// R9 BUG: vmcnt(4) sat at K-tile TOP (after the barrier).  vmcnt is PER-WAVE;
// wave X read rows DMA'd by wave Y before Y's own wait executed -> race
// (absmax 0.107).  FIX: the wait goes at the END of P4, BEFORE the final
// barrier (wait -> barrier -> read = cross-wave happens-before; this is
// exactly why R6/R7's wait-before-BARR placement was safe).
// Ledger at P4-end (steady): outstanding = B(T+1)4 + A(T+1)4 + B(T+2)4;
// vmcnt(4) drains B(T+1),A(T+1) = all of tile T+1; leaves B(T+2).
// Tail: T=NT-2 ends vmcnt(0) (B(NT) skipped; everything NT-1 reads must
// land); last tile stages nothing, no wait needed, 0 outstanding at epilogue.
// Grid: 384 blocks 1D, bijective XCD chunk swizzle (384%8==0).
// Epilogue: Q/K row bounce (Q pre-scaled 0.125*log2e); V transpose -> vT.
// ---------------------------------------------------------------------------
__global__ __launch_bounds__(512, 2) void qkv_kernel(
    const u16* __restrict__ A, const u16* __restrict__ B,
    u16* __restrict__ qk, u16* __restrict__ vT, int K) {
  __shared__ u16 lds[2][4][8192];   // [parity][A0,A1,B0,B1][128x64 u16] 128 KiB

  const int t = threadIdx.x;        // 0..511
  const int lane = t & 63, lr = lane & 15, qd = lane >> 4;
  const int w = t >> 6, wm = w >> 2, wn = w & 3;
  const int L = (blockIdx.x & 7) * 48 + (blockIdx.x >> 3);  // XCD chunk swizzle
  const int m0 = (L / 12) * 256, n0 = (L % 12) * 256;

  // staging: thread t covers 16B at row t>>3 (0..63 per gload), inverse-swz col
  const int srow = t >> 3;
  const int scol = ((t & 7) ^ (srow & 7)) * 8;   // u16
  const u16* Asrc = A + (size_t)(m0 + srow) * K + scol;
  const u16* Bsrc = B + (size_t)(n0 + srow) * K + scol;
  const int wvb = (t & ~63) * 8;                 // wave-uniform u16 base

  const int NT = K >> 6;            // 16 K-tiles
  floatx4 acc[8][4] = {};           // [QR*4+mi][QC*2+nj]

  const int bh2 = wn >> 1, brow0 = (wn & 1) * 64;
  const int csw0 = (qd * 8) ^ ((lr & 7) * 8);
  const int csw1 = (32 + qd * 8) ^ ((lr & 7) * 8);

  // HT: 0=A0(rows 0-127), 1=A1(128-255), 2=B0(cols 0-127), 3=B1(128-255)
#define STG(PR, HT, TK) do { \
    const u16* g_ = (((HT) < 2) ? Asrc : Bsrc) + \
                    (size_t)(((HT) & 1) * 128) * K + (size_t)(TK) * 64; \
    u16* l_ = &lds[PR][HT][wvb]; \
    gload16(g_, l_); \
    gload16(g_ + (size_t)64 * K, l_ + 4096); } while (0)

  bf16x8 af[4][2], bf0[2][2], bf1[2][2];
#define READ_A(PR, QR) do { _Pragma("unroll") for (int mi = 0; mi < 4; ++mi) { \
    const u16* p_ = &lds[PR][wm][((QR) * 64 + mi * 16 + lr) * 64]; \
    af[mi][0] = ld8(p_ + csw0); af[mi][1] = ld8(p_ + csw1); } } while (0)
#define READ_B(PR, QC, BF) do { _Pragma("unroll") for (int nj = 0; nj < 2; ++nj) { \
    const u16* p_ = &lds[PR][2 + bh2][(brow0 + (QC) * 32 + nj * 16 + lr) * 64]; \
    BF[nj][0] = ld8(p_ + csw0); BF[nj][1] = ld8(p_ + csw1); } } while (0)
#define MFMAQ(QR, QC, BF) do { __builtin_amdgcn_s_setprio(1); \
    _Pragma("unroll") for (int mi = 0; mi < 4; ++mi) \
    _Pragma("unroll") for (int nj = 0; nj < 2; ++nj) { \
      acc[(QR)*4+mi][(QC)*2+nj] = mfma16(af[mi][0], BF[nj][0], acc[(QR)*4+mi][(QC)*2+nj]); \
      acc[(QR)*4+mi][(QC)*2+nj] = mfma16(af[mi][1], BF[nj][1], acc[(QR)*4+mi][(QC)*2+nj]); } \
    __builtin_amdgcn_s_setprio(0); } while (0)

  // WEND sits AFTER P4's MFMA and BEFORE the final barrier (the fix).
#define KTILE(T, P, Q, WEND) do { \
    READ_A(P, 0); READ_B(P, 0, bf0); \
    if ((T) + 1 < NT) STG(Q, 0, (T) + 1); \
    BARR; LGKM0; MFMAQ(0, 0, bf0); BARR; \
    READ_B(P, 1, bf1); \
    if ((T) + 1 < NT) STG(Q, 1, (T) + 1); \
    BARR; LGKM0; MFMAQ(0, 1, bf1); BARR; \
    READ_A(P, 1); \
    if ((T) + 2 < NT) STG(P, 2, (T) + 2); \
    BARR; LGKM0; MFMAQ(1, 0, bf0); BARR; \
    if ((T) + 2 < NT) STG(P, 3, (T) + 2); \
    BARR; MFMAQ(1, 1, bf1); WEND; BARR; \
  } while (0)

  // prologue issue order: B0(T0),B1(T0),A0(T0),A1(T0),B0(T1),B1(T1);
  // vmcnt(4) drains T0's 8 loads, leaves B(T1); wait BEFORE barrier (safe).
  STG(0, 2, 0); STG(0, 3, 0);
  STG(0, 0, 0); STG(0, 1, 0);
  STG(1, 2, 1); STG(1, 3, 1);
  VMW4; BARR;

  for (int T = 0; T < NT - 2; ++T) {
    const int p = T & 1;
    KTILE(T, p, p ^ 1, VMW4);
  }
  { const int p = (NT - 2) & 1; KTILE(NT - 2, p, p ^ 1, VMW0); }
  { const int p = (NT - 1) & 1; KTILE(NT - 1, p, p ^ 1, VMNOP); }
#undef STG
#undef READ_A
#undef READ_B
#undef MFMAQ
#undef KTILE

  // ---- epilogue: 0 DMAs outstanding; final barrier passed; reuse LDS ----
  // D layout: col(N)=lane&15, row(M)=(lane>>4)*4+i  [m89/m91]
  // acc[r] covers rows wm*128 + (r>>2)*64 + (r&3)*16  (verified R9 audit)
  u16* flat = &lds[0][0][0];
  const bool isV = (n0 >= 2 * CC);   // block-uniform (n0 multiple of 256)
  if (!isV) {
    const float qs = (n0 < CC) ? 0.18033688011f : 1.0f;
    u16* Tw = flat + w * (32 * 72);  // per-wave [32 rows][72]
    const int C0 = n0 + wn * 64;
#pragma unroll
    for (int rg = 0; rg < 4; ++rg) {   // 4 groups of 32 rows
#pragma unroll
      for (int fh = 0; fh < 2; ++fh)
#pragma unroll
        for (int nj = 0; nj < 4; ++nj)
#pragma unroll
          for (int i = 0; i < 4; ++i)
            Tw[(fh * 16 + qd * 4 + i) * 72 + nj * 16 + lr] =
                f2bf(acc[rg * 2 + fh][nj][i] * qs);
      const int R0 = m0 + wm * 128 + rg * 32;
#pragma unroll
      for (int s = 0; s < 4; ++s) {
        const int rl = s * 8 + (lane >> 3);
        const int c0 = (lane & 7) * 8;
        *(bf16x8*)&qk[(size_t)(R0 + rl) * (2 * CC) + C0 + c0] =
            ld8(&Tw[rl * 72 + c0]);
      }
    }
  } else {
    u16* Tv = flat + w * (64 * 72);  // per-wave [64 dims][72]
    const int bI = m0 >> 11;
    const int tbase = (m0 & (TT - 1)) + wm * 128;
    const int dim0 = (n0 - 2 * CC) + wn * 64;
#pragma unroll
    for (int th = 0; th < 2; ++th) {   // two 64-t halves
#pragma unroll
      for (int nj = 0; nj < 4; ++nj)
#pragma unroll
        for (int fh = 0; fh < 4; ++fh)
#pragma unroll
          for (int i = 0; i < 4; ++i)
            Tv[(nj * 16 + lr) * 72 + fh * 16 + qd * 4 + i] =
                f2bf(acc[th * 4 + fh][nj][i]);
#pragma unroll
      for (int s = 0; s < 8; ++s) {
        const int dl = s * 8 + (lane >> 3);
        const int t0 = (lane & 7) * 8;
        *(bf16x8*)&vT[((size_t)(bI << 10) + dim0 + dl) * TT + tbase + th * 64 + t0] =
            ld8(&Tv[dl * 72 + t0]);
      }
    }
  }
}

// ---------------------------------------------------------------------------
// 128x128 GEMM, BK=32, 256 thr = 4 waves.  global_load_lds staging; one
// barrier per K-iter (R4, verified).  proj: 512 blocks, self-balancing.
// ---------------------------------------------------------------------------
__global__ __launch_bounds__(256) void gemm_kernel(
    const u16* __restrict__ A, const u16* __restrict__ B,
    const float* __restrict__ bias, float* __restrict__ outf,
    int M, int N, int K) {
  __shared__ u16 smem[2][2][2 * TSZ];   // 32 KB

  const int t = threadIdx.x;
  const int w = t >> 6, lane = t & 63, lr = lane & 15, qd = lane >> 4;
  const int wm = w >> 1, wn = w & 1;
  const int m0 = blockIdx.y * 128, n0 = blockIdx.x * 128;

  const int sr = t >> 2;
  const int sc = (t & 3) * 8;
  const int wb = (t & ~63) * 8;
  const u16* Ag = A + (size_t)(m0 + sr) * K + sc;
  const u16* Bg = B + (size_t)(n0 + sr) * K + sc;

  floatx4 acc[4][4] = {};

  {
    u16* sA = &smem[0][0][0];
    u16* sB = &smem[0][1][0];
    gload16(Ag,                  &sA[wb]);
    gload16(Ag + (size_t)64 * K, &sA[TSZ + wb]);
    gload16(Bg,                  &sB[wb]);
    gload16(Bg + (size_t)64 * K, &sB[TSZ + wb]);
  }
  __syncthreads();

  for (int k0 = 0; k0 < K; k0 += 32) {
    const int p = (k0 >> 5) & 1;
    if (k0 + 32 < K) {
      u16* sA = &smem[p ^ 1][0][0];
      u16* sB = &smem[p ^ 1][1][0];
      gload16(Ag + k0 + 32,                  &sA[wb]);
      gload16(Ag + (size_t)64 * K + k0 + 32, &sA[TSZ + wb]);
      gload16(Bg + k0 + 32,                  &sB[wb]);
      gload16(Bg + (size_t)64 * K + k0 + 32, &sB[TSZ + wb]);
    }
    const u16* sA = &smem[p][0][0];
    const u16* sB = &smem[p][1][0];

    bf16x8 af[4], bf[4];
#pragma unroll
    for (int mj = 0; mj < 4; ++mj) af[mj] = ld8(&sA[(wm * 64 + mj * 16 + lr) * TS + qd * 8]);
#pragma unroll
    for (int nj = 0; nj < 4; ++nj) bf[nj] = ld8(&sB[(wn * 64 + nj * 16 + lr) * TS + qd * 8]);
#pragma unroll
    for (int mj = 0; mj < 4; ++mj)
#pragma unroll
      for (int nj = 0; nj < 4; ++nj)
        acc[mj][nj] = mfma16(af[mj], bf[nj], acc[mj][nj]);
    __syncthreads();
  }

  const int rowg0 = m0 + wm * 64;
  const int colg0 = n0 + wn * 64;
#pragma unroll
  for (int nj = 0; nj < 4; ++nj) {
    const int col = colg0 + nj * 16 + lr;
    const float bv = bias[col];
#pragma unroll
    for (int mj = 0; mj < 4; ++mj)
#pragma unroll
      for (int i = 0; i < 4; ++i)
        outf[(size_t)(rowg0 + mj * 16 + qd * 4 + i) * N + col] = acc[mj][nj][i] + bv;
  }
}

// ---------------------------------------------------------------------------
// Causal flash attention (R4 version, verified).  Wave = 16 q, block = 64 q.
// K/V staging via global_load_lds, one barrier per kt (__syncthreads drains
// vmcnt(0) before s_barrier -> cross-wave DMA visibility is safe here).
// In-register P via permlane (R3).  Q pre-scaled by 0.125*log2e.
// ---------------------------------------------------------------------------
__global__ __launch_bounds__(256, 5) void attn_kernel(const u16* __restrict__ qk,
                                                      const u16* __restrict__ vT,
                                                      u16* __restrict__ att) {
  __shared__ u16 sKV[2][4][TSZ];      // 32768 B

  const int t = threadIdx.x;
  const int w = t >> 6, lane = t & 63, lr = lane & 15, qd = lane >> 4;
  const int qtile = 31 - blockIdx.y;  // LPT
  const int bh = blockIdx.x;
  const int b = bh >> 4, h = bh & 15;
  const int q0 = qtile * 64;
  const u16* qbase = qk + (size_t)b * TT * (2 * CC);

  const u16* qp = qbase + (size_t)(q0 + w * 16 + lr) * (2 * CC) + h * HD;
  const bf16x8 qf0 = ld8(qp + qd * 8);
  const bf16x8 qf1 = ld8(qp + 32 + qd * 8);

  const int sr = t >> 2, sc = (t & 3) * 8;
  const int wb = (t & ~63) * 8;
  const u16* Kg = qbase + (size_t)sr * (2 * CC) + CC + h * HD + sc;
  const u16* Vg = vT + ((size_t)bh * HD + sr) * TT + sc;

  float lsum = 0.f;
  floatx4 o[4] = {};
  const int myq = q0 + w * 16 + lr;

  {
    u16* b0 = &sKV[0][0][0];
    gload16(Kg,      &b0[wb]);
    gload16(Kg + 32, &b0[TSZ + wb]);
    gload16(Vg,      &b0[2 * TSZ + wb]);
    gload16(Vg + 32, &b0[3 * TSZ + wb]);
  }
  __syncthreads();

  for (int kt = 0; kt <= qtile; ++kt) {
    if (kt < qtile) {
      const int kn = (kt + 1) * 64;
      u16* bn = &sKV[(kt + 1) & 1][0][0];
      gload16(Kg + (size_t)kn * (2 * CC),      &bn[wb]);
      gload16(Kg + (size_t)kn * (2 * CC) + 32, &bn[TSZ + wb]);
      gload16(Vg + kn,                         &bn[2 * TSZ + wb]);
      gload16(Vg + kn + 32,                    &bn[3 * TSZ + wb]);
    }

    const u16* sK0 = &sKV[kt & 1][0][0];
    const u16* sK1 = &sKV[kt & 1][1][0];
    const u16* sV0 = &sKV[kt & 1][2][0];
    const u16* sV1 = &sKV[kt & 1][3][0];

    floatx4 s[4] = {};
#pragma unroll
    for (int j = 0; j < 4; ++j) {
      bf16x8 kf0 = ld8(&sK0[(j * 16 + lr) * TS + qd * 8]);
      bf16x8 kf1 = ld8(&sK1[(j * 16 + lr) * TS + qd * 8]);
      s[j] = mfma16(kf0, qf0, s[j]);
      s[j] = mfma16(kf1, qf1, s[j]);
    }

    const bool diag = (kt == qtile);
    unsigned W[4][2];
#pragma unroll
    for (int j = 0; j < 4; ++j) {
      float p[4];
#pragma unroll
      for (int i = 0; i < 4; ++i) {
        p[i] = __builtin_amdgcn_exp2f(s[j][i]);
        if (diag) {
          const int key = kt * 64 + j * 16 + qd * 4 + i;
          p[i] = (key <= myq) ? p[i] : 0.f;
        }
        lsum += p[i];
      }
      W[j][0] = __builtin_amdgcn_perm(__float_as_uint(p[1]), __float_as_uint(p[0]), 0x07060302);
      W[j][1] = __builtin_amdgcn_perm(__float_as_uint(p[3]), __float_as_uint(p[2]), 0x07060302);
    }

    uint4 F0, F1;
    qd_xchg(W[0][0], W[1][0], F0.x, F0.z);
    qd_xchg(W[0][1], W[1][1], F0.y, F0.w);
    qd_xchg(W[2][0], W[3][0], F1.x, F1.z);
    qd_xchg(W[2][1], W[3][1], F1.y, F1.w);
    const bf16x8 pf0 = __builtin_bit_cast(bf16x8, F0);
    const bf16x8 pf1 = __builtin_bit_cast(bf16x8, F1);

#pragma unroll
    for (int j = 0; j < 4; ++j) {
      bf16x8 vf0 = ld8(&sV0[(j * 16 + lr) * TS + qd * 8]);
      bf16x8 vf1 = ld8(&sV1[(j * 16 + lr) * TS + qd * 8]);
      o[j] = mfma16(pf0, vf0, o[j]);
      o[j] = mfma16(pf1, vf1, o[j]);
    }
    __syncthreads();
  }

  lsum += __shfl_xor(lsum, 16);
  lsum += __shfl_xor(lsum, 32);
  float linv[4];
#pragma unroll
  for (int i = 0; i < 4; ++i) linv[i] = 1.0f / __shfl(lsum, qd * 4 + i);

#pragma unroll
  for (int j = 0; j < 4; ++j)
#pragma unroll
    for (int i = 0; i < 4; ++i) {
      const size_t row = (size_t)b * TT + q0 + w * 16 + qd * 4 + i;
      att[row * CC + h * HD + j * 16 + lr] = f2bf(o[j][i] * linv[i]);
    }
}

// ---------------------------------------------------------------------------
// ws layout (bytes):
//   xb   0        .. 16 MiB   bf16 [8192][1024]
//   waT  16 MiB   .. 22 MiB   bf16 [3072][1024]
//   wpT  22 MiB   .. 24 MiB   bf16 [1024][1024]
//   qk   24 MiB   .. 56 MiB   bf16 [8192][2048]   (Q|K, Q pre-scaled)
//   vT   56 MiB   .. 72 MiB   bf16 [4*1024][2048] (V^T per (b,dim))
//   att  72 MiB   .. 88 MiB   bf16 [8192][1024]
// ---------------------------------------------------------------------------
extern "C" void kernel_launch(void* const* d_in, const int* in_sizes, int n_in,
                              void* d_out, int out_size, void* d_ws, size_t ws_size,
                              hipStream_t stream) {
  const float* x      = (const float*)d_in[0];
  const float* w_attn = (const float*)d_in[1];
  const float* w_proj = (const float*)d_in[2];
  const float* b_proj = (const float*)d_in[3];
  float* out = (float*)d_out;

  char* ws = (char*)d_ws;
  u16* xb  = (u16*)(ws + 0);
  u16* waT = (u16*)(ws + 16777216);
  u16* wpT = (u16*)(ws + 23068672);
  u16* qk  = (u16*)(ws + 25165824);
  u16* vT  = (u16*)(ws + 58720256);
  u16* att = (u16*)(ws + 75497472);

  // fused prep: tobf16 (8192 blocks) + w_attn^T (768) + w_proj^T (256)
  prep_kernel<<<9216, 256, 0, stream>>>((const float4*)x, (ushort4*)xb,
                                        w_attn, waT, w_proj, wpT);

  // qkv = x @ w_attn  (M=8192, N=3072, K=1024) -> qk + vT
  qkv_kernel<<<384, 512, 0, stream>>>(xb, waT, qk, vT, CC);

  // attention: grid (bh, qtile) -> same-bh blocks share an XCD; LPT in y
  attn_kernel<<<dim3(64, 32), 256, 0, stream>>>(qk, vT, att);

  // out = att @ w_proj + b_proj  (M=8192, N=1024, K=1024), fp32 out
  gemm_kernel<<<dim3(8, 64), 256, 0, stream>>>(att, wpT, b_proj, out,
                                               BT, CC, CC);
}

// Round 11
// 221.011 us; speedup vs baseline: 1.0481x; 1.0481x over previous
//
#include <hip/hip_runtime.h>

// Problem constants
#define BB 4
#define TT 2048
#define CC 1024
#define C3 3072
#define HH 16
#define HD 64
#define BT 8192   // BB*TT

#define TS 32
#define TSZ (64 * TS)   // u16 elements per 64-row sub-tile (4 KB)

typedef __bf16 bf16x8 __attribute__((ext_vector_type(8)));
typedef float floatx4 __attribute__((ext_vector_type(4)));
typedef unsigned uintx2 __attribute__((ext_vector_type(2)));
typedef unsigned short u16;

__device__ __forceinline__ u16 f2bf(float f) {
  union { float f; unsigned u; } a; a.f = f;
  return (u16)((a.u + 0x7fffu + ((a.u >> 16) & 1u)) >> 16);  // RNE
}
__device__ __forceinline__ bf16x8 ld8(const u16* p) { return *(const bf16x8*)p; }
__device__ __forceinline__ floatx4 mfma16(bf16x8 a, bf16x8 b, floatx4 c) {
  return __builtin_amdgcn_mfma_f32_16x16x32_bf16(a, b, c, 0, 0, 0);
}

// Async global->LDS, 16B/lane. LDS dest = wave-uniform base + lane*16 (m104).
__device__ __forceinline__ void gload16(const u16* g, u16* l) {
  __builtin_amdgcn_global_load_lds(
      (const __attribute__((address_space(1))) void*)g,
      (__attribute__((address_space(3))) void*)l, 16, 0, 0);
}

// qd-group redistribution via permlane32/16_swap (verified R3):
//   r0 = [a@0, a@2, b@0, b@2], r1 = [a@1, a@3, b@1, b@3]  (by qd group)
__device__ __forceinline__ void qd_xchg(unsigned a, unsigned b,
                                        unsigned& r0, unsigned& r1) {
  uintx2 t = __builtin_amdgcn_permlane32_swap(a, b, false, false);
  uintx2 r = __builtin_amdgcn_permlane16_swap(t[0], t[1], false, false);
  r0 = r[0]; r1 = r[1];
}

// compiler-fence + hw barrier (no vmcnt drain, unlike __syncthreads)
#define BARR do { asm volatile("" ::: "memory"); \
                  __builtin_amdgcn_s_barrier(); \
                  asm volatile("" ::: "memory"); } while (0)
#define VMW4 asm volatile("s_waitcnt vmcnt(4)" ::: "memory")
#define VMW0 asm volatile("s_waitcnt vmcnt(0)" ::: "memory")

// ---------------------------------------------------------------------------
// Fused prep kernel (R8, verified):
//   blocks [0, 8192)    : fp32 -> bf16 for x
//   blocks [8192, 8960) : w_attn -> waT transpose
//   blocks [8960, 9216) : w_proj -> wpT transpose
// ---------------------------------------------------------------------------
__global__ __launch_bounds__(256) void prep_kernel(
    const float4* __restrict__ x4, ushort4* __restrict__ xb4,
    const float* __restrict__ w_attn, u16* __restrict__ waT,
    const float* __restrict__ w_proj, u16* __restrict__ wpT) {
  __shared__ float s[64][65];
  const int t = threadIdx.x;
  const int bid = blockIdx.x;

  if (bid < 8192) {                 // --- tobf16 ---
    const int i = bid * 256 + t;
    float4 v = x4[i];
    ushort4 o; o.x = f2bf(v.x); o.y = f2bf(v.y); o.z = f2bf(v.z); o.w = f2bf(v.w);
    xb4[i] = o;
    return;
  }

  const float* src; u16* dst; int N, bx, by;
  if (bid < 8960) { const int b2 = bid - 8192; src = w_attn; dst = waT; N = C3;
                    bx = b2 % 48; by = b2 / 48; }
  else            { const int b2 = bid - 8960; src = w_proj; dst = wpT; N = CC;
                    bx = b2 % 16; by = b2 / 16; }
  const int K = CC;
  const int r = t >> 4;
  const int c = (t & 15) * 4;
  const int k0 = by * 64, n0 = bx * 64;
#pragma unroll
  for (int i = 0; i < 4; ++i) {
    float4 v = *(const float4*)&src[(size_t)(k0 + r + i * 16) * N + n0 + c];
    s[r + i * 16][c + 0] = v.x; s[r + i * 16][c + 1] = v.y;
    s[r + i * 16][c + 2] = v.z; s[r + i * 16][c + 3] = v.w;
  }
  __syncthreads();
#pragma unroll
  for (int i = 0; i < 4; ++i) {
    const int nn = r + i * 16;
    ushort4 o;
    o.x = f2bf(s[c + 0][nn]); o.y = f2bf(s[c + 1][nn]);
    o.z = f2bf(s[c + 2][nn]); o.w = f2bf(s[c + 3][nn]);
    *(ushort4*)&dst[(size_t)(n0 + nn) * K + k0 + c] = o;
  }
}

// ---------------------------------------------------------------------------
// R7/R8-verified qkv GEMM (best measured: 63.0 us, 845 TF).  256x128 tile,
// 4 phases per 2 K-tiles, 512 thr = 8 waves (4M x 2N), 64x64 out per wave.
// R10 post-mortem: the deeper m201-geometry port (256x256, 8 barriers/K-tile,
// 1 block/CU) measured 67.6 us -- barrier drain with no co-resident block.
// This 2-barrier-per-K-tile shape is the local optimum for this problem.
// LDS 96 KiB: lds[parity][ A 256x64 | B 128x64 ] u16, 16B-granular XOR
// swizzle LDS[row][c] = G[row][c ^ ((row&7)*8)] (inverse-swizzled global src
// on gload_lds + swizzled ds_read -> conflict-free; verified 328K).
// Schedule (2 K-tiles per iter, 4 phases, 2 barriers/K-tile):
//   ph0: stage B(2i+1)->buf1; read buf0 A + B01; 16 MFMA;            BARR
//   ph1: stage A(2i+2)->buf0; read buf0 B23;     16 MFMA; vmcnt(4);  BARR
//   ph2: stage B(2i+2)->buf0; read buf1 A + B01; 16 MFMA;            BARR
//   ph3: stage A(2i+3)->buf1; read buf1 B23;     16 MFMA; vmcnt(4);  BARR
// Waits sit BEFORE barriers (cross-wave DMA visibility -- R9/R10 lesson).
// Last iter drains with vmcnt(0).
// MODE 1: qkv epilogue (Q pre-scaled 0.125*log2e; Q/K row bounce; V
//         transpose bounce -> vT).  MODE 2: fp32 out + bias, direct.
// ---------------------------------------------------------------------------
template<int MODE>
__global__ __launch_bounds__(512, 2) void gemm256_kernel(
    const u16* __restrict__ A, const u16* __restrict__ B,
    const float* __restrict__ bias, float* __restrict__ outf,
    u16* __restrict__ qk, u16* __restrict__ vT, int N, int K) {
  __shared__ u16 lds[2][24576];   // [parity][A:0..16383 | B:16384..24575] 96 KiB

  const int t = threadIdx.x;      // 0..511
  const int lane = t & 63, lr = lane & 15, qd = lane >> 4;
  const int w = t >> 6, wm = w >> 1, wn = w & 1;
  const int m0 = blockIdx.y * 256, n0 = blockIdx.x * 128;

  const int srow = t >> 3;
  const int scol = ((t & 7) ^ (srow & 7)) * 8;   // u16
  const u16* Asrc = A + (size_t)(m0 + srow) * K + scol;
  const u16* Bsrc = B + (size_t)(n0 + srow) * K + scol;
  const int wvb = (t & ~63) * 8;                 // wave-uniform u16 base

  const int NT = K >> 6;          // 64-wide K-tiles (16)
  floatx4 acc[4][4] = {};

  const int abase = (wm * 64 + lr) * 64;
  const int bbase = (wn * 64 + lr) * 64;
  const int csw0 = (qd * 8) ^ ((lr & 7) * 8);
  const int csw1 = (32 + qd * 8) ^ ((lr & 7) * 8);

#define STG_A(PR, QA, TK) do { if ((TK) < NT) \
    gload16(Asrc + (size_t)((QA) * 64) * K + (TK) * 64, \
            &lds[PR][(QA) * 4096 + wvb]); } while (0)
#define STG_B(PR, HB, TK) do { if ((TK) < NT) \
    gload16(Bsrc + (size_t)((HB) * 64) * K + (TK) * 64, \
            &lds[PR][16384 + (HB) * 4096 + wvb]); } while (0)

  bf16x8 af[4][2], bf[2][2];
#define READ_A(PR) do { _Pragma("unroll") for (int mi = 0; mi < 4; ++mi) { \
    const u16* p_ = &lds[PR][mi * 1024 + abase]; \
    af[mi][0] = ld8(p_ + csw0); af[mi][1] = ld8(p_ + csw1); } } while (0)
#define READ_B(PR, NJ0) do { _Pragma("unroll") for (int nj = 0; nj < 2; ++nj) { \
    const u16* p_ = &lds[PR][16384 + ((NJ0) + nj) * 1024 + bbase]; \
    bf[nj][0] = ld8(p_ + csw0); bf[nj][1] = ld8(p_ + csw1); } } while (0)
#define MFMA16(NJ0) do { __builtin_amdgcn_s_setprio(1); _Pragma("unroll") \
    for (int mi = 0; mi < 4; ++mi) _Pragma("unroll") for (int nj = 0; nj < 2; ++nj) { \
      acc[mi][(NJ0) + nj] = mfma16(af[mi][0], bf[nj][0], acc[mi][(NJ0) + nj]); \
      acc[mi][(NJ0) + nj] = mfma16(af[mi][1], bf[nj][1], acc[mi][(NJ0) + nj]); } \
    __builtin_amdgcn_s_setprio(0); } while (0)

  // prologue: A(0),B(0) -> buf0; A(1) -> buf1.  vmcnt(4) leaves A(1) in flight.
  STG_A(0, 0, 0); STG_A(0, 1, 0); STG_A(0, 2, 0); STG_A(0, 3, 0);
  STG_B(0, 0, 0); STG_B(0, 1, 0);
  STG_A(1, 0, 1); STG_A(1, 1, 1); STG_A(1, 2, 1); STG_A(1, 3, 1);
  VMW4; BARR;

  const int NITER = NT >> 1;
  for (int it = 0; it < NITER; ++it) {
    const int T1 = 2 * it + 1, T2 = 2 * it + 2, T3 = 2 * it + 3;
    const bool last = (it == NITER - 1);
    // ph0: even tile (buf0) first half
    STG_B(1, 0, T1); STG_B(1, 1, T1);
    READ_A(0); READ_B(0, 0); MFMA16(0);
    BARR;
    // ph1: even tile second half (af reused)
    STG_A(0, 0, T2); STG_A(0, 1, T2); STG_A(0, 2, T2); STG_A(0, 3, T2);
    READ_B(0, 2); MFMA16(2);
    if (last) { VMW0; } else { VMW4; }
    BARR;
    // ph2: odd tile (buf1) first half
    STG_B(0, 0, T2); STG_B(0, 1, T2);
    READ_A(1); READ_B(1, 0); MFMA16(0);
    BARR;
    // ph3: odd tile second half
    STG_A(1, 0, T3); STG_A(1, 1, T3); STG_A(1, 2, T3); STG_A(1, 3, T3);
    READ_B(1, 2); MFMA16(2);
    if (last) { VMW0; } else { VMW4; }
    BARR;
  }
#undef STG_A
#undef STG_B
#undef READ_A
#undef READ_B
#undef MFMA16

  // ---- epilogue: all DMAs landed (vmcnt0 on last iter) + final barrier ----
  // D layout: col(N)=lane&15, row(M)=(lane>>4)*4+i  [m89/m91]
  u16* flat = &lds[0][0];
  if constexpr (MODE == 2) {
    const int rowg0 = m0 + wm * 64;
    const int colg0 = n0 + wn * 64;
#pragma unroll
    for (int nj = 0; nj < 4; ++nj) {
      const int col = colg0 + nj * 16 + lr;
      const float bv = bias[col];
#pragma unroll
      for (int mi = 0; mi < 4; ++mi)
#pragma unroll
        for (int i = 0; i < 4; ++i)
          outf[(size_t)(rowg0 + mi * 16 + qd * 4 + i) * N + col] = acc[mi][nj][i] + bv;
    }
  } else {
    const bool isV = (n0 >= 2 * CC);   // block-uniform
    if (!isV) {
      const float qs = (n0 < CC) ? 0.18033688011f : 1.0f;
      u16* Tw = flat + w * (32 * 72);  // per-wave [32 rows][72]
      const int C0 = n0 + wn * 64;
#pragma unroll
      for (int mi2 = 0; mi2 < 2; ++mi2) {
#pragma unroll
        for (int mh = 0; mh < 2; ++mh)
#pragma unroll
          for (int nj = 0; nj < 4; ++nj)
#pragma unroll
            for (int i = 0; i < 4; ++i)
              Tw[(mh * 16 + qd * 4 + i) * 72 + nj * 16 + lr] =
                  f2bf(acc[mi2 * 2 + mh][nj][i] * qs);
        const int R0 = m0 + wm * 64 + mi2 * 32;
#pragma unroll
        for (int s = 0; s < 4; ++s) {
          const int rl = s * 8 + (lane >> 3);
          const int c0 = (lane & 7) * 8;
          *(bf16x8*)&qk[(size_t)(R0 + rl) * (2 * CC) + C0 + c0] =
              ld8(&Tw[rl * 72 + c0]);
        }
      }
    } else {
      u16* Tv = flat + w * (64 * 72);  // per-wave [64 dims][72]
      const int bI = m0 >> 11;
      const int tbase = (m0 & (TT - 1)) + wm * 64;
      const int dim0 = (n0 - 2 * CC) + wn * 64;
#pragma unroll
      for (int nj = 0; nj < 4; ++nj)
#pragma unroll
        for (int mi = 0; mi < 4; ++mi)
#pragma unroll
          for (int i = 0; i < 4; ++i)
            Tv[(nj * 16 + lr) * 72 + mi * 16 + qd * 4 + i] =
                f2bf(acc[mi][nj][i]);
#pragma unroll
      for (int s = 0; s < 8; ++s) {
        const int dl = s * 8 + (lane >> 3);
        const int t0 = (lane & 7) * 8;
        *(bf16x8*)&vT[((size_t)(bI << 10) + dim0 + dl) * TT + tbase + t0] =
            ld8(&Tv[dl * 72 + t0]);
      }
    }
  }
}

// ---------------------------------------------------------------------------
// 128x128 GEMM, BK=32, 256 thr = 4 waves.  global_load_lds staging; one
// barrier per K-iter (R4, verified).  proj: 512 blocks, 32 KB LDS,
// ~4-5 resident blocks/CU -> self-balancing (R7 lesson).
// ---------------------------------------------------------------------------
__global__ __launch_bounds__(256) void gemm_kernel(
    const u16* __restrict__ A, const u16* __restrict__ B,
    const float* __restrict__ bias, float* __restrict__ outf,
    int M, int N, int K) {
  __shared__ u16 smem[2][2][2 * TSZ];   // 32 KB

  const int t = threadIdx.x;
  const int w = t >> 6, lane = t & 63, lr = lane & 15, qd = lane >> 4;
  const int wm = w >> 1, wn = w & 1;
  const int m0 = blockIdx.y * 128, n0 = blockIdx.x * 128;

  const int sr = t >> 2;
  const int sc = (t & 3) * 8;
  const int wb = (t & ~63) * 8;
  const u16* Ag = A + (size_t)(m0 + sr) * K + sc;
  const u16* Bg = B + (size_t)(n0 + sr) * K + sc;

  floatx4 acc[4][4] = {};

  {
    u16* sA = &smem[0][0][0];
    u16* sB = &smem[0][1][0];
    gload16(Ag,                  &sA[wb]);
    gload16(Ag + (size_t)64 * K, &sA[TSZ + wb]);
    gload16(Bg,                  &sB[wb]);
    gload16(Bg + (size_t)64 * K, &sB[TSZ + wb]);
  }
  __syncthreads();

  for (int k0 = 0; k0 < K; k0 += 32) {
    const int p = (k0 >> 5) & 1;
    if (k0 + 32 < K) {
      u16* sA = &smem[p ^ 1][0][0];
      u16* sB = &smem[p ^ 1][1][0];
      gload16(Ag + k0 + 32,                  &sA[wb]);
      gload16(Ag + (size_t)64 * K + k0 + 32, &sA[TSZ + wb]);
      gload16(Bg + k0 + 32,                  &sB[wb]);
      gload16(Bg + (size_t)64 * K + k0 + 32, &sB[TSZ + wb]);
    }
    const u16* sA = &smem[p][0][0];
    const u16* sB = &smem[p][1][0];

    bf16x8 af[4], bf[4];
#pragma unroll
    for (int mj = 0; mj < 4; ++mj) af[mj] = ld8(&sA[(wm * 64 + mj * 16 + lr) * TS + qd * 8]);
#pragma unroll
    for (int nj = 0; nj < 4; ++nj) bf[nj] = ld8(&sB[(wn * 64 + nj * 16 + lr) * TS + qd * 8]);
#pragma unroll
    for (int mj = 0; mj < 4; ++mj)
#pragma unroll
      for (int nj = 0; nj < 4; ++nj)
        acc[mj][nj] = mfma16(af[mj], bf[nj], acc[mj][nj]);
    __syncthreads();
  }

  const int rowg0 = m0 + wm * 64;
  const int colg0 = n0 + wn * 64;
#pragma unroll
  for (int nj = 0; nj < 4; ++nj) {
    const int col = colg0 + nj * 16 + lr;
    const float bv = bias[col];
#pragma unroll
    for (int mj = 0; mj < 4; ++mj)
#pragma unroll
      for (int i = 0; i < 4; ++i)
        outf[(size_t)(rowg0 + mj * 16 + qd * 4 + i) * N + col] = acc[mj][nj][i] + bv;
  }
}

// ---------------------------------------------------------------------------
// Causal flash attention (R4 version, verified).  Wave = 16 q, block = 64 q.
// K/V staging via global_load_lds, one barrier per kt (__syncthreads drains
// vmcnt(0) before s_barrier -> cross-wave DMA visibility safe).
// In-register P via permlane (R3).  Q pre-scaled by 0.125*log2e.
// ---------------------------------------------------------------------------
__global__ __launch_bounds__(256, 5) void attn_kernel(const u16* __restrict__ qk,
                                                      const u16* __restrict__ vT,
                                                      u16* __restrict__ att) {
  __shared__ u16 sKV[2][4][TSZ];      // 32768 B

  const int t = threadIdx.x;
  const int w = t >> 6, lane = t & 63, lr = lane & 15, qd = lane >> 4;
  const int qtile = 31 - blockIdx.y;  // LPT
  const int bh = blockIdx.x;
  const int b = bh >> 4, h = bh & 15;
  const int q0 = qtile * 64;
  const u16* qbase = qk + (size_t)b * TT * (2 * CC);

  const u16* qp = qbase + (size_t)(q0 + w * 16 + lr) * (2 * CC) + h * HD;
  const bf16x8 qf0 = ld8(qp + qd * 8);
  const bf16x8 qf1 = ld8(qp + 32 + qd * 8);

  const int sr = t >> 2, sc = (t & 3) * 8;
  const int wb = (t & ~63) * 8;
  const u16* Kg = qbase + (size_t)sr * (2 * CC) + CC + h * HD + sc;
  const u16* Vg = vT + ((size_t)bh * HD + sr) * TT + sc;

  float lsum = 0.f;
  floatx4 o[4] = {};
  const int myq = q0 + w * 16 + lr;

  {
    u16* b0 = &sKV[0][0][0];
    gload16(Kg,      &b0[wb]);
    gload16(Kg + 32, &b0[TSZ + wb]);
    gload16(Vg,      &b0[2 * TSZ + wb]);
    gload16(Vg + 32, &b0[3 * TSZ + wb]);
  }
  __syncthreads();

  for (int kt = 0; kt <= qtile; ++kt) {
    if (kt < qtile) {
      const int kn = (kt + 1) * 64;
      u16* bn = &sKV[(kt + 1) & 1][0][0];
      gload16(Kg + (size_t)kn * (2 * CC),      &bn[wb]);
      gload16(Kg + (size_t)kn * (2 * CC) + 32, &bn[TSZ + wb]);
      gload16(Vg + kn,                         &bn[2 * TSZ + wb]);
      gload16(Vg + kn + 32,                    &bn[3 * TSZ + wb]);
    }

    const u16* sK0 = &sKV[kt & 1][0][0];
    const u16* sK1 = &sKV[kt & 1][1][0];
    const u16* sV0 = &sKV[kt & 1][2][0];
    const u16* sV1 = &sKV[kt & 1][3][0];

    floatx4 s[4] = {};
#pragma unroll
    for (int j = 0; j < 4; ++j) {
      bf16x8 kf0 = ld8(&sK0[(j * 16 + lr) * TS + qd * 8]);
      bf16x8 kf1 = ld8(&sK1[(j * 16 + lr) * TS + qd * 8]);
      s[j] = mfma16(kf0, qf0, s[j]);
      s[j] = mfma16(kf1, qf1, s[j]);
    }

    const bool diag = (kt == qtile);
    unsigned W[4][2];
#pragma unroll
    for (int j = 0; j < 4; ++j) {
      float p[4];
#pragma unroll
      for (int i = 0; i < 4; ++i) {
        p[i] = __builtin_amdgcn_exp2f(s[j][i]);
        if (diag) {
          const int key = kt * 64 + j * 16 + qd * 4 + i;
          p[i] = (key <= myq) ? p[i] : 0.f;
        }
        lsum += p[i];
      }
      W[j][0] = __builtin_amdgcn_perm(__float_as_uint(p[1]), __float_as_uint(p[0]), 0x07060302);
      W[j][1] = __builtin_amdgcn_perm(__float_as_uint(p[3]), __float_as_uint(p[2]), 0x07060302);
    }

    uint4 F0, F1;
    qd_xchg(W[0][0], W[1][0], F0.x, F0.z);
    qd_xchg(W[0][1], W[1][1], F0.y, F0.w);
    qd_xchg(W[2][0], W[3][0], F1.x, F1.z);
    qd_xchg(W[2][1], W[3][1], F1.y, F1.w);
    const bf16x8 pf0 = __builtin_bit_cast(bf16x8, F0);
    const bf16x8 pf1 = __builtin_bit_cast(bf16x8, F1);

#pragma unroll
    for (int j = 0; j < 4; ++j) {
      bf16x8 vf0 = ld8(&sV0[(j * 16 + lr) * TS + qd * 8]);
      bf16x8 vf1 = ld8(&sV1[(j * 16 + lr) * TS + qd * 8]);
      o[j] = mfma16(pf0, vf0, o[j]);
      o[j] = mfma16(pf1, vf1, o[j]);
    }
    __syncthreads();
  }

  lsum += __shfl_xor(lsum, 16);
  lsum += __shfl_xor(lsum, 32);
  float linv[4];
#pragma unroll
  for (int i = 0; i < 4; ++i) linv[i] = 1.0f / __shfl(lsum, qd * 4 + i);

#pragma unroll
  for (int j = 0; j < 4; ++j)
#pragma unroll
    for (int i = 0; i < 4; ++i) {
      const size_t row = (size_t)b * TT + q0 + w * 16 + qd * 4 + i;
      att[row * CC + h * HD + j * 16 + lr] = f2bf(o[j][i] * linv[i]);
    }
}

// ---------------------------------------------------------------------------
// ws layout (bytes):
//   xb   0        .. 16 MiB   bf16 [8192][1024]
//   waT  16 MiB   .. 22 MiB   bf16 [3072][1024]
//   wpT  22 MiB   .. 24 MiB   bf16 [1024][1024]
//   qk   24 MiB   .. 56 MiB   bf16 [8192][2048]   (Q|K, Q pre-scaled)
//   vT   56 MiB   .. 72 MiB   bf16 [4*1024][2048] (V^T per (b,dim))
//   att  72 MiB   .. 88 MiB   bf16 [8192][1024]
// ---------------------------------------------------------------------------
extern "C" void kernel_launch(void* const* d_in, const int* in_sizes, int n_in,
                              void* d_out, int out_size, void* d_ws, size_t ws_size,
                              hipStream_t stream) {
  const float* x      = (const float*)d_in[0];
  const float* w_attn = (const float*)d_in[1];
  const float* w_proj = (const float*)d_in[2];
  const float* b_proj = (const float*)d_in[3];
  float* out = (float*)d_out;

  char* ws = (char*)d_ws;
  u16* xb  = (u16*)(ws + 0);
  u16* waT = (u16*)(ws + 16777216);
  u16* wpT = (u16*)(ws + 23068672);
  u16* qk  = (u16*)(ws + 25165824);
  u16* vT  = (u16*)(ws + 58720256);
  u16* att = (u16*)(ws + 75497472);

  // fused prep: tobf16 (8192 blocks) + w_attn^T (768) + w_proj^T (256)
  prep_kernel<<<9216, 256, 0, stream>>>((const float4*)x, (ushort4*)xb,
                                        w_attn, waT, w_proj, wpT);

  // qkv = x @ w_attn  (M=8192, N=3072, K=1024) -> qk + vT
  // grid 24x32 = 768 blocks = 3 rounds (amortizes block->CU imbalance)
  gemm256_kernel<1><<<dim3(24, 32), 512, 0, stream>>>(xb, waT, nullptr, nullptr,
                                                      qk, vT, C3, CC);

  // attention: grid (bh, qtile) -> same-bh blocks share an XCD; LPT in y
  attn_kernel<<<dim3(64, 32), 256, 0, stream>>>(qk, vT, att);

  // out = att @ w_proj + b_proj  (M=8192, N=1024, K=1024), fp32 out
  // 128^2 tiles: 512 blocks, ~4-5 resident/CU, self-balancing
  gemm_kernel<<<dim3(8, 64), 256, 0, stream>>>(att, wpT, b_proj, out,
                                               BT, CC, CC);
}